// Round 12
// baseline (124.654 us; speedup 1.0000x reference)
//
#include <hip/hip_runtime.h>
#include <math.h>

#define NN 100000
#define NE 1600000
#define F_IN 64
#define HID 16
#define OUTF 32
#define BKT_SHIFT 6
#define BKT_NODES 64
#define NBKT 1563               // ceil(NN/64)
#define SRCM 0x1FFFF
#define CAP_REG 2048            // fixed region per bucket (mean 1024, sd 32)
#define CAP_LDS 1536            // fast-path LDS sort capacity
#define PBLK2 500
#define EPB2 3200               // 500*3200 = 1.6M exact
#define OVF_MAX 4096

__device__ __forceinline__ unsigned bf16r(float f) {   // round-to-nearest-even bf16
    unsigned u = __float_as_uint(f);
    return (u + 0x7FFFu + ((u >> 16) & 1u)) >> 16;
}
__device__ __forceinline__ float bfa(unsigned p) { return __uint_as_float(p << 16); }
__device__ __forceinline__ float bfd(unsigned p) { return __uint_as_float(p & 0xFFFF0000u); }
__device__ __forceinline__ float bfh(unsigned short v) { return __uint_as_float(((unsigned)v) << 16); }

__device__ __forceinline__ void acc8(uint4 hv, float u, float* s0, float* s1) {
    unsigned w[4] = {hv.x, hv.y, hv.z, hv.w};
#pragma unroll
    for (int q = 0; q < 4; ++q) {
        float lo = __uint_as_float(w[q] << 16);
        float hi = __uint_as_float(w[q] & 0xFFFF0000u);
        s0[2 * q]     += lo; s1[2 * q]     = fmaf(u, lo, s1[2 * q]);
        s0[2 * q + 1] += hi; s1[2 * q + 1] = fmaf(u, hi, s1[2 * q + 1]);
    }
}
__device__ __forceinline__ void acc4(uint4 ap, float u, float* a) {
    unsigned w[4] = {ap.x, ap.y, ap.z, ap.w};
#pragma unroll
    for (int q = 0; q < 4; ++q)
        a[q] += fmaf(u, bfd(w[q]), bfa(w[q]));
}

// ---- zero gcur/novf ----
__global__ __launch_bounds__(256) void zeroG_kernel(int* __restrict__ gcur,
                                                    int* __restrict__ novf) {
    int t = blockIdx.x * 256 + threadIdx.x;
    if (t < NBKT) gcur[t] = 0;
    if (t == NBKT) novf[0] = 0;
}

// ---- fused partition: vec-hist -> scan -> claim -> LDS-sorted stage -> writeout ----
__global__ __launch_bounds__(1024) void partF_kernel(const int* __restrict__ ei,
                                                     const float* __restrict__ ea,
                                                     int* __restrict__ gcur,
                                                     int* __restrict__ novf,
                                                     int4* __restrict__ ovf,
                                                     int2* __restrict__ bkt) {
    __shared__ int hcnt[NBKT];
    __shared__ int hbase[NBKT];
    __shared__ int lbase[NBKT];
    __shared__ int s[1024];
    __shared__ int2 sbuf[EPB2];                // 25.6 KB
    __shared__ unsigned short bid[EPB2];       // 6.4 KB
    int t = threadIdx.x, blk = blockIdx.x;
    for (int i = t; i < NBKT; i += 1024) hcnt[i] = 0;
    __syncthreads();
    int beg = blk * EPB2;
    int4 d4 = make_int4(0, 0, 0, 0);
    bool act = (4 * t) < EPB2;  // t < 800
    if (act) {
        d4 = *(const int4*)(ei + NE + beg + 4 * t);
        atomicAdd(&hcnt[d4.x >> BKT_SHIFT], 1);
        atomicAdd(&hcnt[d4.y >> BKT_SHIFT], 1);
        atomicAdd(&hcnt[d4.z >> BKT_SHIFT], 1);
        atomicAdd(&hcnt[d4.w >> BKT_SHIFT], 1);
    }
    __syncthreads();
    int i0 = 2 * t, i1 = 2 * t + 1;
    int v0 = (i0 < NBKT) ? hcnt[i0] : 0;
    int v1 = (i1 < NBKT) ? hcnt[i1] : 0;
    s[t] = v0 + v1;
    __syncthreads();
    for (int off = 1; off < 1024; off <<= 1) {
        int xv = (t >= off) ? s[t - off] : 0;
        __syncthreads();
        s[t] += xv;
        __syncthreads();
    }
    int run = (t == 0) ? 0 : s[t - 1];
    if (i0 < NBKT) lbase[i0] = run;
    if (i1 < NBKT) lbase[i1] = run + v0;
    __syncthreads();
    for (int i = t; i < NBKT; i += 1024) {
        int c = hcnt[i];
        hbase[i] = c ? atomicAdd(&gcur[i], c) : 0;
        hcnt[i] = 0;
    }
    __syncthreads();
    if (act) {
        int4 s4 = *(const int4*)(ei + beg + 4 * t);
        float4 u4 = *(const float4*)(ea + beg + 4 * t);
        int dst[4] = {d4.x, d4.y, d4.z, d4.w};
        int src[4] = {s4.x, s4.y, s4.z, s4.w};
        float uu[4] = {u4.x, u4.y, u4.z, u4.w};
#pragma unroll
        for (int k = 0; k < 4; ++k) {
            int b = dst[k] >> BKT_SHIFT;
            int r = atomicAdd(&hcnt[b], 1);
            int lp = lbase[b] + r;
            sbuf[lp] = make_int2(src[k] | ((dst[k] & (BKT_NODES - 1)) << 17),
                                 __float_as_int(uu[k]));
            bid[lp] = (unsigned short)b;
        }
    }
    __syncthreads();
    for (int i = t; i < EPB2; i += 1024) {
        int2 pk = sbuf[i];
        int b = bid[i];
        int p = hbase[b] + (i - lbase[b]);
        if (p < CAP_REG) {
            bkt[(size_t)b * CAP_REG + p] = pk;
        } else {
            int o = atomicAdd(novf, 1);
            if (o < OVF_MAX)
                ovf[o] = make_int4(b * BKT_NODES + (((unsigned)pk.x) >> 17), pk.x & SRCM, pk.y, 0);
        }
    }
}

// ---- layer-1 projection ----
__global__ __launch_bounds__(256) void proj1_kernel(const float* __restrict__ x,
                                                    const float* __restrict__ W1,
                                                    const float* __restrict__ root1,
                                                    const float* __restrict__ bias1,
                                                    unsigned* __restrict__ ab1p,
                                                    float* __restrict__ r1) {
    __shared__ float w[2 * F_IN * HID];
    __shared__ float wr[F_IN * HID];
    __shared__ float bb[HID];
    for (int i = threadIdx.x; i < 2 * F_IN * HID; i += 256) w[i] = W1[i];
    for (int i = threadIdx.x; i < F_IN * HID; i += 256) wr[i] = root1[i];
    if (threadIdx.x < HID) bb[threadIdx.x] = bias1[threadIdx.x];
    __syncthreads();
    int n = blockIdx.x * 256 + threadIdx.x;
    if (n >= NN) return;
    float accA[HID], accB[HID], accR[HID];
#pragma unroll
    for (int o = 0; o < HID; ++o) { accA[o] = 0.f; accB[o] = 0.f; accR[o] = bb[o]; }
    const float4* xr4 = (const float4*)(x + (size_t)n * F_IN);
    for (int f4 = 0; f4 < F_IN / 4; ++f4) {
        float4 xv4 = xr4[f4];
        float xs[4] = {xv4.x, xv4.y, xv4.z, xv4.w};
#pragma unroll
        for (int q = 0; q < 4; ++q) {
            int f = f4 * 4 + q;
            float xv = xs[q];
            const float* w0 = &w[f * HID];
            const float* w1 = &w[F_IN * HID + f * HID];
            const float* w2 = &wr[f * HID];
#pragma unroll
            for (int o = 0; o < HID; ++o) {
                accA[o] = fmaf(xv, w0[o], accA[o]);
                accB[o] = fmaf(xv, w1[o], accB[o]);
                accR[o] = fmaf(xv, w2[o], accR[o]);
            }
        }
    }
    unsigned* ar = ab1p + (size_t)n * HID;
    float* rr = r1 + (size_t)n * HID;
#pragma unroll
    for (int o = 0; o < HID; ++o) {
        ar[o] = bf16r(accA[o]) | (bf16r(accB[o] - accA[o]) << 16);
        rr[o] = accR[o];
    }
}

// ---- layer-1: LDS sort + deep-MLP register accumulate + ELU -> h16; persist sorted+segg ----
__global__ __launch_bounds__(512) void gather1_kernel(const int* __restrict__ gcur,
                                                      const int* __restrict__ novf,
                                                      const int4* __restrict__ ovf,
                                                      int2* __restrict__ bkt,
                                                      const unsigned* __restrict__ ab1p,
                                                      const float* __restrict__ r1,
                                                      unsigned short* __restrict__ h16,
                                                      float* __restrict__ dinv,
                                                      int* __restrict__ segg) {
    __shared__ int2 raw[CAP_LDS];           // 12 KB
    __shared__ int2 sorted[CAP_LDS];        // 12 KB
    __shared__ int cnt[BKT_NODES], cur[BKT_NODES], segb[BKT_NODES + 1];
    __shared__ float degsL[BKT_NODES];
    int t = threadIdx.x;
    int b = blockIdx.x;
    int tot = gcur[b];
    int beg = b * CAP_REG;
    if (t < BKT_NODES) { cnt[t] = 0; cur[t] = 0; degsL[t] = 0.f; }
    __syncthreads();
    int nodeBase = b * BKT_NODES;

    if (tot <= CAP_LDS) {
        // vectorized stage (2 edges per int4)
        int nv = tot >> 1;
        const int4* g4 = (const int4*)(bkt + beg);
        int4* r4 = (int4*)raw;
        for (int i = t; i < nv; i += 512) r4[i] = g4[i];
        if (t == 0 && (tot & 1)) raw[tot - 1] = bkt[beg + tot - 1];
        __syncthreads();
        for (int e = t; e < tot; e += 512)
            atomicAdd(&cnt[((unsigned)raw[e].x) >> 17], 1);
        __syncthreads();
        if (t < BKT_NODES) {
            int v = cnt[t];
            int sc = v;
#pragma unroll
            for (int off = 1; off < 64; off <<= 1) {
                int o = __shfl_up(sc, off, 64);
                if (t >= off) sc += o;
            }
            segb[t] = sc - v;
            if (t == 63) segb[64] = sc;
        }
        __syncthreads();
        for (int e = t; e < tot; e += 512) {
            int2 pk = raw[e];
            int loc = ((unsigned)pk.x) >> 17;
            int pos = segb[loc] + atomicAdd(&cur[loc], 1);
            sorted[pos] = pk;
        }
        __syncthreads();
        // persist sorted order + segment bounds (vectorized)
        int4* s4 = (int4*)sorted;
        int4* o4 = (int4*)(bkt + beg);
        for (int i = t; i < nv; i += 512) o4[i] = s4[i];
        if (t == 0 && (tot & 1)) bkt[beg + tot - 1] = sorted[tot - 1];
        if (t <= BKT_NODES) segg[b * (BKT_NODES + 1) + t] = segb[t];
        // deep-MLP accumulate: 8 lanes/node = 2 edge-subsets x 4 feature-quarters
        int node = t >> 3;
        int sub = (t >> 2) & 1;
        int jq = t & 3;
        int s0 = segb[node], e2 = segb[node + 1];
        float acc[4] = {0.f, 0.f, 0.f, 0.f};
        int e = s0 + sub;
        for (; e + 6 < e2; e += 8) {
            int2 p0 = sorted[e];
            int2 p1 = sorted[e + 2];
            int2 p2 = sorted[e + 4];
            int2 p3 = sorted[e + 6];
            uint4 a0 = *(const uint4*)(ab1p + ((size_t)(p0.x & SRCM) << 4) + (jq << 2));
            uint4 a1 = *(const uint4*)(ab1p + ((size_t)(p1.x & SRCM) << 4) + (jq << 2));
            uint4 a2 = *(const uint4*)(ab1p + ((size_t)(p2.x & SRCM) << 4) + (jq << 2));
            uint4 a3 = *(const uint4*)(ab1p + ((size_t)(p3.x & SRCM) << 4) + (jq << 2));
            acc4(a0, __int_as_float(p0.y), acc);
            acc4(a1, __int_as_float(p1.y), acc);
            acc4(a2, __int_as_float(p2.y), acc);
            acc4(a3, __int_as_float(p3.y), acc);
        }
        for (; e < e2; e += 2) {
            int2 pk = sorted[e];
            uint4 ap = *(const uint4*)(ab1p + ((size_t)(pk.x & SRCM) << 4) + (jq << 2));
            acc4(ap, __int_as_float(pk.y), acc);
        }
#pragma unroll
        for (int k = 0; k < 4; ++k) acc[k] += __shfl_xor(acc[k], 4);
        if (sub == 0) {
            int n = nodeBase + node;
            if (n < NN) {
                float d0 = 1.f / (float)max(e2 - s0, 1);
                float4 rv = *(const float4*)(r1 + ((size_t)n << 4) + (jq << 2));
                float rr[4] = {rv.x, rv.y, rv.z, rv.w};
                unsigned hw[4];
#pragma unroll
                for (int k = 0; k < 4; ++k) {
                    float v = acc[k] * d0 + rr[k];
                    hw[k] = bf16r(v > 0.f ? v : expm1f(v));
                }
                *(uint2*)(h16 + ((size_t)n << 4) + (jq << 2)) =
                    make_uint2(hw[0] | (hw[1] << 16), hw[2] | (hw[3] << 16));
                if (jq == 0) dinv[n] = d0;
            }
        }
    } else {
        // ---- legacy atomic path (bucket overflow; statistically never) ----
        float* accL = (float*)raw;
        int inreg = min(tot, CAP_REG);
        int end = beg + inreg;
        for (int i = t; i < BKT_NODES * HID; i += 512) accL[i] = 0.f;
        __syncthreads();
        int j = t & (HID - 1);
        int g = t >> 4;
        for (int e = beg + g; e < end; e += 32) {
            int2 pk = bkt[e];
            unsigned p = ab1p[(size_t)(pk.x & SRCM) * HID + j];
            atomicAdd(&accL[(((unsigned)pk.x) >> 17) * HID + j],
                      fmaf(__int_as_float(pk.y), bfd(p), bfa(p)));
            if (j == 0) atomicAdd(&degsL[((unsigned)pk.x) >> 17], 1.f);
        }
        int ovn = min(novf[0], OVF_MAX);
        for (int o = 0; o < ovn; ++o) {
            int4 ent = ovf[o];
            int loc = ent.x - nodeBase;
            if (loc >= 0 && loc < BKT_NODES && g == 0) {
                unsigned p = ab1p[(size_t)ent.y * HID + j];
                atomicAdd(&accL[loc * HID + j], fmaf(__int_as_float(ent.z), bfd(p), bfa(p)));
                if (j == 0) atomicAdd(&degsL[loc], 1.f);
            }
        }
        __syncthreads();
        if (t < BKT_NODES) degsL[t] = 1.f / fmaxf(degsL[t], 1.f);
        if (t == 0) segg[b * (BKT_NODES + 1)] = -1;  // mark unsorted
        __syncthreads();
#pragma unroll
        for (int it = 0; it < BKT_NODES * HID / 512; ++it) {
            int idx = it * 512 + t;
            int nl = idx >> 4, jj = idx & (HID - 1);
            int n = nodeBase + nl;
            if (n < NN) {
                float v = accL[idx] * degsL[nl] + r1[(size_t)n * HID + jj];
                h16[(size_t)n * HID + jj] = (unsigned short)bf16r(v > 0.f ? v : expm1f(v));
            }
        }
        if (t < BKT_NODES && nodeBase + t < NN) dinv[nodeBase + t] = degsL[t];
    }
}

// ---- layer-2: barrier-free deep-MLP aggregate from pre-sorted global bucket ----
__global__ __launch_bounds__(512) void gather2_kernel(const int* __restrict__ gcur,
                                                      const int* __restrict__ novf,
                                                      const int4* __restrict__ ovf,
                                                      const int2* __restrict__ bkt,
                                                      const unsigned short* __restrict__ h16,
                                                      const float* __restrict__ W2,
                                                      const float* __restrict__ root2,
                                                      const float* __restrict__ bias2,
                                                      const float* __restrict__ dinv,
                                                      const int* __restrict__ segg,
                                                      float* __restrict__ out) {
    __shared__ int segb[BKT_NODES + 1];
    __shared__ float s0L[BKT_NODES * HID];  // 4 KB
    __shared__ float s1L[BKT_NODES * HID];  // 4 KB
    __shared__ float hloc[BKT_NODES * HID]; // 4 KB
    __shared__ float w20[HID * OUTF], w2d[HID * OUTF], wr[HID * OUTF];
    __shared__ float bb[OUTF];
    int t = threadIdx.x;
    for (int i = t; i < HID * OUTF; i += 512) {
        float a = W2[i];
        w20[i] = a;
        w2d[i] = W2[HID * OUTF + i] - a;
        wr[i] = root2[i];
    }
    if (t < OUTF) bb[t] = bias2[t];
    int b = blockIdx.x;
    int tot = gcur[b];
    int beg = b * CAP_REG;
    int nodeBase = b * BKT_NODES;
    if (t <= BKT_NODES) segb[t] = segg[b * (BKT_NODES + 1) + t];
    // stage own-node h rows (uint4 = 8 bf16 per lane)
    if (t < BKT_NODES * HID / 8) {
        uint4 hv = ((const uint4*)(h16 + ((size_t)nodeBase << 4)))[t];
        unsigned w4[4] = {hv.x, hv.y, hv.z, hv.w};
#pragma unroll
        for (int q = 0; q < 4; ++q) {
            hloc[t * 8 + 2 * q]     = __uint_as_float(w4[q] << 16);
            hloc[t * 8 + 2 * q + 1] = __uint_as_float(w4[q] & 0xFFFF0000u);
        }
    }
    __syncthreads();

    if (tot <= CAP_LDS && segb[0] != -1) {
        const int2* sp = bkt + beg;   // pre-sorted by gather1
        int node = t >> 3;
        int sub = (t >> 1) & 3;
        int jh = t & 1;
        int s = segb[node], e2 = segb[node + 1];
        float s0[8] = {0.f, 0.f, 0.f, 0.f, 0.f, 0.f, 0.f, 0.f};
        float s1[8] = {0.f, 0.f, 0.f, 0.f, 0.f, 0.f, 0.f, 0.f};
        int e = s + sub;
        for (; e + 12 < e2; e += 16) {
            int2 p0 = sp[e];
            int2 p1 = sp[e + 4];
            int2 p2 = sp[e + 8];
            int2 p3 = sp[e + 12];
            uint4 h0 = *(const uint4*)(h16 + ((size_t)(p0.x & SRCM) << 4) + (jh << 3));
            uint4 h1 = *(const uint4*)(h16 + ((size_t)(p1.x & SRCM) << 4) + (jh << 3));
            uint4 h2 = *(const uint4*)(h16 + ((size_t)(p2.x & SRCM) << 4) + (jh << 3));
            uint4 h3 = *(const uint4*)(h16 + ((size_t)(p3.x & SRCM) << 4) + (jh << 3));
            acc8(h0, __int_as_float(p0.y), s0, s1);
            acc8(h1, __int_as_float(p1.y), s0, s1);
            acc8(h2, __int_as_float(p2.y), s0, s1);
            acc8(h3, __int_as_float(p3.y), s0, s1);
        }
        for (; e < e2; e += 4) {
            int2 pk = sp[e];
            uint4 hv = *(const uint4*)(h16 + ((size_t)(pk.x & SRCM) << 4) + (jh << 3));
            acc8(hv, __int_as_float(pk.y), s0, s1);
        }
#pragma unroll
        for (int k = 0; k < 8; ++k) {
            s0[k] += __shfl_xor(s0[k], 2); s0[k] += __shfl_xor(s0[k], 4);
            s1[k] += __shfl_xor(s1[k], 2); s1[k] += __shfl_xor(s1[k], 4);
        }
        if (sub == 0) {
            int base = node * HID + jh * 8;
#pragma unroll
            for (int k = 0; k < 8; ++k) { s0L[base + k] = s0[k]; s1L[base + k] = s1[k]; }
        }
        __syncthreads();
    } else {
        int inreg = min(tot, CAP_REG);
        int end = beg + inreg;
        for (int i = t; i < BKT_NODES * HID; i += 512) { s0L[i] = 0.f; s1L[i] = 0.f; }
        __syncthreads();
        int j = t & (HID - 1);
        int g = t >> 4;
        for (int e = beg + g; e < end; e += 32) {
            int2 pk = bkt[e];
            float hvv = bfh(h16[(size_t)(pk.x & SRCM) * HID + j]);
            int l = ((unsigned)pk.x) >> 17;
            atomicAdd(&s0L[l * HID + j], hvv);
            atomicAdd(&s1L[l * HID + j], __int_as_float(pk.y) * hvv);
        }
        int ovn = min(novf[0], OVF_MAX);
        for (int o = 0; o < ovn; ++o) {
            int4 ent = ovf[o];
            int loc = ent.x - nodeBase;
            if (loc >= 0 && loc < BKT_NODES && g == 0) {
                float hvv = bfh(h16[(size_t)ent.y * HID + j]);
                atomicAdd(&s0L[loc * HID + j], hvv);
                atomicAdd(&s1L[loc * HID + j], __int_as_float(ent.z) * hvv);
            }
        }
        __syncthreads();
    }

#pragma unroll
    for (int it = 0; it < BKT_NODES * OUTF / 512; ++it) {  // 4
        int idx = it * 512 + t;
        int nl = idx >> 5, jj = idx & (OUTF - 1);
        int n = nodeBase + nl;
        float v = 0.f;
        if (n < NN) {
            float msum = 0.f;
            const float* S0 = &s0L[nl * HID];
            const float* S1 = &s1L[nl * HID];
#pragma unroll
            for (int f = 0; f < HID; ++f)
                msum += S0[f] * w20[f * OUTF + jj] + S1[f] * w2d[f * OUTF + jj];
            v = msum * dinv[n] + bb[jj];
            const float* hr = &hloc[nl * HID];
#pragma unroll
            for (int f = 0; f < HID; ++f)
                v = fmaf(hr[f], wr[f * OUTF + jj], v);
        }
        float m = v;
#pragma unroll
        for (int mask = 16; mask >= 1; mask >>= 1) m = fmaxf(m, __shfl_xor(m, mask));
        float ex = expf(v - m);
        float sm = ex;
#pragma unroll
        for (int mask = 16; mask >= 1; mask >>= 1) sm += __shfl_xor(sm, mask);
        if (n < NN) out[(size_t)n * OUTF + jj] = v - m - logf(sm);
    }
}

extern "C" void kernel_launch(void* const* d_in, const int* in_sizes, int n_in,
                              void* d_out, int out_size, void* d_ws, size_t ws_size,
                              hipStream_t stream) {
    const float* x     = (const float*)d_in[0];
    const int*   ei    = (const int*)d_in[1];
    const float* ea    = (const float*)d_in[3];
    const float* W1    = (const float*)d_in[4];
    const float* root1 = (const float*)d_in[5];
    const float* bias1 = (const float*)d_in[6];
    const float* W2    = (const float*)d_in[7];
    const float* root2 = (const float*)d_in[8];
    const float* bias2 = (const float*)d_in[9];
    float* out = (float*)d_out;
    float* ws  = (float*)d_ws;

    const size_t N = NN;
    int*            gcur = (int*)(ws);                        // 1563
    int*            novf = (int*)(ws + 2000);                 // 1
    int4*           ovf  = (int4*)(ws + 2048);                // OVF_MAX int4
    float*          dinv = ws + 20000;                        // 100000
    int*            segg = (int*)(ws + 120000);               // NBKT*65 = 101595
    float*          r1   = ws + 222000;                       // 16N
    unsigned*       ab1p = (unsigned*)(ws + 222000 + 16 * N); // 16N u32
    unsigned short* h16  = (unsigned short*)(ws + 222000 + 32 * N); // 16N u16
    int2*           bkt  = (int2*)(ws + 222000 + 40 * N);     // NBKT*CAP_REG int2

    int nbN = (NN + 255) / 256;
    zeroG_kernel<<<(NBKT + 256) / 256, 256, 0, stream>>>(gcur, novf);
    partF_kernel<<<PBLK2, 1024, 0, stream>>>(ei, ea, gcur, novf, ovf, bkt);
    proj1_kernel<<<nbN, 256, 0, stream>>>(x, W1, root1, bias1, ab1p, r1);
    gather1_kernel<<<NBKT, 512, 0, stream>>>(gcur, novf, ovf, bkt, ab1p, r1, h16, dinv, segg);
    gather2_kernel<<<NBKT, 512, 0, stream>>>(gcur, novf, ovf, bkt, h16, W2, root2, bias2, dinv, segg, out);
}

// Round 13
// 120.018 us; speedup vs baseline: 1.0386x; 1.0386x over previous
//
#include <hip/hip_runtime.h>
#include <math.h>

#define NN 100000
#define NE 1600000
#define F_IN 64
#define HID 16
#define OUTF 32
#define BKT_SHIFT 6
#define BKT_NODES 64
#define NBKT 1563               // ceil(NN/64)
#define SRCM 0x1FFFF
#define CAP_REG 2048            // fixed region per bucket (mean 1024, sd 32)
#define CAP_LDS 1536            // fast-path LDS sort capacity
#define PBLK2 500
#define EPB2 3200               // 500*3200 = 1.6M exact
#define OVF_MAX 4096

__device__ __forceinline__ unsigned bf16r(float f) {
    unsigned u = __float_as_uint(f);
    return (u + 0x7FFFu + ((u >> 16) & 1u)) >> 16;
}
__device__ __forceinline__ float bfa(unsigned p) { return __uint_as_float(p << 16); }
__device__ __forceinline__ float bfd(unsigned p) { return __uint_as_float(p & 0xFFFF0000u); }
__device__ __forceinline__ float bfh(unsigned short v) { return __uint_as_float(((unsigned)v) << 16); }

__device__ __forceinline__ void acc8(uint4 hv, float u, float* s0, float* s1) {
    unsigned w[4] = {hv.x, hv.y, hv.z, hv.w};
#pragma unroll
    for (int q = 0; q < 4; ++q) {
        float lo = __uint_as_float(w[q] << 16);
        float hi = __uint_as_float(w[q] & 0xFFFF0000u);
        s0[2 * q]     += lo; s1[2 * q]     = fmaf(u, lo, s1[2 * q]);
        s0[2 * q + 1] += hi; s1[2 * q + 1] = fmaf(u, hi, s1[2 * q + 1]);
    }
}
__device__ __forceinline__ void acc4(uint4 ap, float u, float* a) {
    unsigned w[4] = {ap.x, ap.y, ap.z, ap.w};
#pragma unroll
    for (int q = 0; q < 4; ++q)
        a[q] += fmaf(u, bfd(w[q]), bfa(w[q]));
}

__global__ __launch_bounds__(256) void zeroG_kernel(int* __restrict__ gcur,
                                                    int* __restrict__ novf) {
    int t = blockIdx.x * 256 + threadIdx.x;
    if (t < NBKT) gcur[t] = 0;
    if (t == NBKT) novf[0] = 0;
}

// ---- fused partition (unchanged from R12) ----
__global__ __launch_bounds__(1024) void partF_kernel(const int* __restrict__ ei,
                                                     const float* __restrict__ ea,
                                                     int* __restrict__ gcur,
                                                     int* __restrict__ novf,
                                                     int4* __restrict__ ovf,
                                                     int2* __restrict__ bkt) {
    __shared__ int hcnt[NBKT];
    __shared__ int hbase[NBKT];
    __shared__ int lbase[NBKT];
    __shared__ int s[1024];
    __shared__ int2 sbuf[EPB2];
    __shared__ unsigned short bid[EPB2];
    int t = threadIdx.x, blk = blockIdx.x;
    for (int i = t; i < NBKT; i += 1024) hcnt[i] = 0;
    __syncthreads();
    int beg = blk * EPB2;
    int4 d4 = make_int4(0, 0, 0, 0);
    bool act = (4 * t) < EPB2;
    if (act) {
        d4 = *(const int4*)(ei + NE + beg + 4 * t);
        atomicAdd(&hcnt[d4.x >> BKT_SHIFT], 1);
        atomicAdd(&hcnt[d4.y >> BKT_SHIFT], 1);
        atomicAdd(&hcnt[d4.z >> BKT_SHIFT], 1);
        atomicAdd(&hcnt[d4.w >> BKT_SHIFT], 1);
    }
    __syncthreads();
    int i0 = 2 * t, i1 = 2 * t + 1;
    int v0 = (i0 < NBKT) ? hcnt[i0] : 0;
    int v1 = (i1 < NBKT) ? hcnt[i1] : 0;
    s[t] = v0 + v1;
    __syncthreads();
    for (int off = 1; off < 1024; off <<= 1) {
        int xv = (t >= off) ? s[t - off] : 0;
        __syncthreads();
        s[t] += xv;
        __syncthreads();
    }
    int run = (t == 0) ? 0 : s[t - 1];
    if (i0 < NBKT) lbase[i0] = run;
    if (i1 < NBKT) lbase[i1] = run + v0;
    __syncthreads();
    for (int i = t; i < NBKT; i += 1024) {
        int c = hcnt[i];
        hbase[i] = c ? atomicAdd(&gcur[i], c) : 0;
        hcnt[i] = 0;
    }
    __syncthreads();
    if (act) {
        int4 s4 = *(const int4*)(ei + beg + 4 * t);
        float4 u4 = *(const float4*)(ea + beg + 4 * t);
        int dst[4] = {d4.x, d4.y, d4.z, d4.w};
        int src[4] = {s4.x, s4.y, s4.z, s4.w};
        float uu[4] = {u4.x, u4.y, u4.z, u4.w};
#pragma unroll
        for (int k = 0; k < 4; ++k) {
            int b = dst[k] >> BKT_SHIFT;
            int r = atomicAdd(&hcnt[b], 1);
            int lp = lbase[b] + r;
            sbuf[lp] = make_int2(src[k] | ((dst[k] & (BKT_NODES - 1)) << 17),
                                 __float_as_int(uu[k]));
            bid[lp] = (unsigned short)b;
        }
    }
    __syncthreads();
    for (int i = t; i < EPB2; i += 1024) {
        int2 pk = sbuf[i];
        int b = bid[i];
        int p = hbase[b] + (i - lbase[b]);
        if (p < CAP_REG) {
            bkt[(size_t)b * CAP_REG + p] = pk;
        } else {
            int o = atomicAdd(novf, 1);
            if (o < OVF_MAX)
                ovf[o] = make_int4(b * BKT_NODES + (((unsigned)pk.x) >> 17), pk.x & SRCM, pk.y, 0);
        }
    }
}

// ---- layer-1 projection (unchanged) ----
__global__ __launch_bounds__(256) void proj1_kernel(const float* __restrict__ x,
                                                    const float* __restrict__ W1,
                                                    const float* __restrict__ root1,
                                                    const float* __restrict__ bias1,
                                                    unsigned* __restrict__ ab1p,
                                                    float* __restrict__ r1) {
    __shared__ float w[2 * F_IN * HID];
    __shared__ float wr[F_IN * HID];
    __shared__ float bb[HID];
    for (int i = threadIdx.x; i < 2 * F_IN * HID; i += 256) w[i] = W1[i];
    for (int i = threadIdx.x; i < F_IN * HID; i += 256) wr[i] = root1[i];
    if (threadIdx.x < HID) bb[threadIdx.x] = bias1[threadIdx.x];
    __syncthreads();
    int n = blockIdx.x * 256 + threadIdx.x;
    if (n >= NN) return;
    float accA[HID], accB[HID], accR[HID];
#pragma unroll
    for (int o = 0; o < HID; ++o) { accA[o] = 0.f; accB[o] = 0.f; accR[o] = bb[o]; }
    const float4* xr4 = (const float4*)(x + (size_t)n * F_IN);
    for (int f4 = 0; f4 < F_IN / 4; ++f4) {
        float4 xv4 = xr4[f4];
        float xs[4] = {xv4.x, xv4.y, xv4.z, xv4.w};
#pragma unroll
        for (int q = 0; q < 4; ++q) {
            int f = f4 * 4 + q;
            float xv = xs[q];
            const float* w0 = &w[f * HID];
            const float* w1 = &w[F_IN * HID + f * HID];
            const float* w2 = &wr[f * HID];
#pragma unroll
            for (int o = 0; o < HID; ++o) {
                accA[o] = fmaf(xv, w0[o], accA[o]);
                accB[o] = fmaf(xv, w1[o], accB[o]);
                accR[o] = fmaf(xv, w2[o], accR[o]);
            }
        }
    }
    unsigned* ar = ab1p + (size_t)n * HID;
    float* rr = r1 + (size_t)n * HID;
#pragma unroll
    for (int o = 0; o < HID; ++o) {
        ar[o] = bf16r(accA[o]) | (bf16r(accB[o] - accA[o]) << 16);
        rr[o] = accR[o];
    }
}

// ---- layer-1: 256-thr, small-LDS; count+scatter from global; 4 lanes/node accumulate ----
__global__ __launch_bounds__(256) void gather1_kernel(const int* __restrict__ gcur,
                                                      const int* __restrict__ novf,
                                                      const int4* __restrict__ ovf,
                                                      int2* __restrict__ bkt,
                                                      const unsigned* __restrict__ ab1p,
                                                      const float* __restrict__ r1,
                                                      unsigned short* __restrict__ h16,
                                                      float* __restrict__ dinv,
                                                      int* __restrict__ segg) {
    __shared__ int2 sorted[CAP_LDS];        // 12 KB
    __shared__ int cnt[BKT_NODES], cur[BKT_NODES], segb[BKT_NODES + 1];
    __shared__ float degsL[BKT_NODES];
    int t = threadIdx.x;
    int b = blockIdx.x;
    int tot = gcur[b];
    int beg = b * CAP_REG;
    if (t < BKT_NODES) { cnt[t] = 0; cur[t] = 0; degsL[t] = 0.f; }
    __syncthreads();
    int nodeBase = b * BKT_NODES;

    if (tot <= CAP_LDS) {
        // count (global read #1, L2-resident 12 KB)
        for (int e = t; e < tot; e += 256)
            atomicAdd(&cnt[((unsigned)bkt[beg + e].x) >> 17], 1);
        __syncthreads();
        if (t < BKT_NODES) {
            int v = cnt[t];
            int sc = v;
#pragma unroll
            for (int off = 1; off < 64; off <<= 1) {
                int o = __shfl_up(sc, off, 64);
                if (t >= off) sc += o;
            }
            segb[t] = sc - v;
            if (t == 63) segb[64] = sc;
        }
        __syncthreads();
        // scatter (global read #2) into sorted LDS
        for (int e = t; e < tot; e += 256) {
            int2 pk = bkt[beg + e];
            int loc = ((unsigned)pk.x) >> 17;
            int pos = segb[loc] + atomicAdd(&cur[loc], 1);
            sorted[pos] = pk;
        }
        __syncthreads();
        // persist sorted order + segment bounds (vectorized)
        int nv = tot >> 1;
        int4* s4 = (int4*)sorted;
        int4* o4 = (int4*)(bkt + beg);
        for (int i = t; i < nv; i += 256) o4[i] = s4[i];
        if (t == 0 && (tot & 1)) bkt[beg + tot - 1] = sorted[tot - 1];
        if (t <= BKT_NODES) segg[b * (BKT_NODES + 1) + t] = segb[t];
        // accumulate: 4 lanes/node, one feature-quarter each (no cross-lane reduce)
        int node = t >> 2;
        int jq = t & 3;
        int s0 = segb[node], e2 = segb[node + 1];
        float acc[4] = {0.f, 0.f, 0.f, 0.f};
        int e = s0;
        for (; e + 3 < e2; e += 4) {
            int2 p0 = sorted[e];
            int2 p1 = sorted[e + 1];
            int2 p2 = sorted[e + 2];
            int2 p3 = sorted[e + 3];
            uint4 a0 = *(const uint4*)(ab1p + ((size_t)(p0.x & SRCM) << 4) + (jq << 2));
            uint4 a1 = *(const uint4*)(ab1p + ((size_t)(p1.x & SRCM) << 4) + (jq << 2));
            uint4 a2 = *(const uint4*)(ab1p + ((size_t)(p2.x & SRCM) << 4) + (jq << 2));
            uint4 a3 = *(const uint4*)(ab1p + ((size_t)(p3.x & SRCM) << 4) + (jq << 2));
            acc4(a0, __int_as_float(p0.y), acc);
            acc4(a1, __int_as_float(p1.y), acc);
            acc4(a2, __int_as_float(p2.y), acc);
            acc4(a3, __int_as_float(p3.y), acc);
        }
        for (; e < e2; ++e) {
            int2 pk = sorted[e];
            uint4 ap = *(const uint4*)(ab1p + ((size_t)(pk.x & SRCM) << 4) + (jq << 2));
            acc4(ap, __int_as_float(pk.y), acc);
        }
        int n = nodeBase + node;
        if (n < NN) {
            float d0 = 1.f / (float)max(e2 - s0, 1);
            float4 rv = *(const float4*)(r1 + ((size_t)n << 4) + (jq << 2));
            float rr[4] = {rv.x, rv.y, rv.z, rv.w};
            unsigned hw[4];
#pragma unroll
            for (int k = 0; k < 4; ++k) {
                float v = acc[k] * d0 + rr[k];
                hw[k] = bf16r(v > 0.f ? v : expm1f(v));
            }
            *(uint2*)(h16 + ((size_t)n << 4) + (jq << 2)) =
                make_uint2(hw[0] | (hw[1] << 16), hw[2] | (hw[3] << 16));
            if (jq == 0) dinv[n] = d0;
        }
    } else {
        // ---- legacy atomic path (bucket overflow; statistically never) ----
        float* accL = (float*)sorted;  // 4 KB of the 12 KB buffer
        int inreg = min(tot, CAP_REG);
        int end = beg + inreg;
        for (int i = t; i < BKT_NODES * HID; i += 256) accL[i] = 0.f;
        __syncthreads();
        int j = t & (HID - 1);
        int g = t >> 4;  // 16 groups
        for (int e = beg + g; e < end; e += 16) {
            int2 pk = bkt[e];
            unsigned p = ab1p[(size_t)(pk.x & SRCM) * HID + j];
            atomicAdd(&accL[(((unsigned)pk.x) >> 17) * HID + j],
                      fmaf(__int_as_float(pk.y), bfd(p), bfa(p)));
            if (j == 0) atomicAdd(&degsL[((unsigned)pk.x) >> 17], 1.f);
        }
        int ovn = min(novf[0], OVF_MAX);
        for (int o = 0; o < ovn; ++o) {
            int4 ent = ovf[o];
            int loc = ent.x - nodeBase;
            if (loc >= 0 && loc < BKT_NODES && g == 0) {
                unsigned p = ab1p[(size_t)ent.y * HID + j];
                atomicAdd(&accL[loc * HID + j], fmaf(__int_as_float(ent.z), bfd(p), bfa(p)));
                if (j == 0) atomicAdd(&degsL[loc], 1.f);
            }
        }
        __syncthreads();
        if (t < BKT_NODES) degsL[t] = 1.f / fmaxf(degsL[t], 1.f);
        if (t == 0) segg[b * (BKT_NODES + 1)] = -1;  // mark unsorted
        __syncthreads();
        for (int idx = t; idx < BKT_NODES * HID; idx += 256) {
            int nl = idx >> 4, jj = idx & (HID - 1);
            int n = nodeBase + nl;
            if (n < NN) {
                float v = accL[idx] * degsL[nl] + r1[(size_t)n * HID + jj];
                h16[(size_t)n * HID + jj] = (unsigned short)bf16r(v > 0.f ? v : expm1f(v));
            }
        }
        if (t < BKT_NODES && nodeBase + t < NN) dinv[nodeBase + t] = degsL[t];
    }
}

// ---- layer-2: half-bucket blocks (32 nodes, 256 threads), small LDS ----
#define HB_NODES 32
__global__ __launch_bounds__(256) void gather2_kernel(const int* __restrict__ gcur,
                                                      const int* __restrict__ novf,
                                                      const int4* __restrict__ ovf,
                                                      const int2* __restrict__ bkt,
                                                      const unsigned short* __restrict__ h16,
                                                      const float* __restrict__ W2,
                                                      const float* __restrict__ root2,
                                                      const float* __restrict__ bias2,
                                                      const float* __restrict__ dinv,
                                                      const int* __restrict__ segg,
                                                      float* __restrict__ out) {
    __shared__ int segb[HB_NODES + 1];
    __shared__ int sflag;
    __shared__ float s0L[HB_NODES * HID];   // 2 KB
    __shared__ float s1L[HB_NODES * HID];   // 2 KB
    __shared__ float hloc[HB_NODES * HID];  // 2 KB
    __shared__ float w20[HID * OUTF], w2d[HID * OUTF], wr[HID * OUTF];  // 6 KB
    __shared__ float bb[OUTF];
    int t = threadIdx.x;
    int b2 = blockIdx.x;
    int b = b2 >> 1;
    int h = b2 & 1;
    for (int i = t; i < HID * OUTF; i += 256) {
        float a = W2[i];
        w20[i] = a;
        w2d[i] = W2[HID * OUTF + i] - a;
        wr[i] = root2[i];
    }
    if (t < OUTF) bb[t] = bias2[t];
    int tot = gcur[b];
    int beg = b * CAP_REG;
    int nodeBase = b * BKT_NODES + h * HB_NODES;
    if (t <= HB_NODES) segb[t] = segg[b * (BKT_NODES + 1) + h * HB_NODES + t];
    if (t == 0) sflag = segg[b * (BKT_NODES + 1)];
    // stage own-node h rows (uint4 = 8 bf16 per lane); 32 nodes * 16 = 512 bf16 = 64 uint4
    if (t < HB_NODES * HID / 8) {
        uint4 hv = *(const uint4*)(h16 + ((size_t)nodeBase << 4) + t * 8);
        unsigned w4[4] = {hv.x, hv.y, hv.z, hv.w};
#pragma unroll
        for (int q = 0; q < 4; ++q) {
            hloc[t * 8 + 2 * q]     = __uint_as_float(w4[q] << 16);
            hloc[t * 8 + 2 * q + 1] = __uint_as_float(w4[q] & 0xFFFF0000u);
        }
    }
    __syncthreads();

    if (tot <= CAP_LDS && sflag != -1) {
        const int2* sp = bkt + beg;   // pre-sorted by gather1
        int node = t >> 3;            // 0..31
        int sub = (t >> 1) & 3;
        int jh = t & 1;
        int s = segb[node], e2 = segb[node + 1];
        float s0[8] = {0.f, 0.f, 0.f, 0.f, 0.f, 0.f, 0.f, 0.f};
        float s1[8] = {0.f, 0.f, 0.f, 0.f, 0.f, 0.f, 0.f, 0.f};
        int e = s + sub;
        for (; e + 12 < e2; e += 16) {
            int2 p0 = sp[e];
            int2 p1 = sp[e + 4];
            int2 p2 = sp[e + 8];
            int2 p3 = sp[e + 12];
            uint4 h0 = *(const uint4*)(h16 + ((size_t)(p0.x & SRCM) << 4) + (jh << 3));
            uint4 h1 = *(const uint4*)(h16 + ((size_t)(p1.x & SRCM) << 4) + (jh << 3));
            uint4 h2 = *(const uint4*)(h16 + ((size_t)(p2.x & SRCM) << 4) + (jh << 3));
            uint4 h3 = *(const uint4*)(h16 + ((size_t)(p3.x & SRCM) << 4) + (jh << 3));
            acc8(h0, __int_as_float(p0.y), s0, s1);
            acc8(h1, __int_as_float(p1.y), s0, s1);
            acc8(h2, __int_as_float(p2.y), s0, s1);
            acc8(h3, __int_as_float(p3.y), s0, s1);
        }
        for (; e < e2; e += 4) {
            int2 pk = sp[e];
            uint4 hv = *(const uint4*)(h16 + ((size_t)(pk.x & SRCM) << 4) + (jh << 3));
            acc8(hv, __int_as_float(pk.y), s0, s1);
        }
#pragma unroll
        for (int k = 0; k < 8; ++k) {
            s0[k] += __shfl_xor(s0[k], 2); s0[k] += __shfl_xor(s0[k], 4);
            s1[k] += __shfl_xor(s1[k], 2); s1[k] += __shfl_xor(s1[k], 4);
        }
        if (sub == 0) {
            int base = node * HID + jh * 8;
#pragma unroll
            for (int k = 0; k < 8; ++k) { s0L[base + k] = s0[k]; s1L[base + k] = s1[k]; }
        }
        __syncthreads();
    } else {
        int inreg = min(tot, CAP_REG);
        int end = beg + inreg;
        for (int i = t; i < HB_NODES * HID; i += 256) { s0L[i] = 0.f; s1L[i] = 0.f; }
        __syncthreads();
        int j = t & (HID - 1);
        int g = t >> 4;
        for (int e = beg + g; e < end; e += 16) {
            int2 pk = bkt[e];
            int loc = ((unsigned)pk.x) >> 17;
            if ((loc >> 5) == h) {
                float hvv = bfh(h16[(size_t)(pk.x & SRCM) * HID + j]);
                atomicAdd(&s0L[(loc & 31) * HID + j], hvv);
                atomicAdd(&s1L[(loc & 31) * HID + j], __int_as_float(pk.y) * hvv);
            }
        }
        int ovn = min(novf[0], OVF_MAX);
        for (int o = 0; o < ovn; ++o) {
            int4 ent = ovf[o];
            int loc = ent.x - nodeBase;
            if (loc >= 0 && loc < HB_NODES && g == 0) {
                float hvv = bfh(h16[(size_t)ent.y * HID + j]);
                atomicAdd(&s0L[loc * HID + j], hvv);
                atomicAdd(&s1L[loc * HID + j], __int_as_float(ent.z) * hvv);
            }
        }
        __syncthreads();
    }

#pragma unroll
    for (int it = 0; it < HB_NODES * OUTF / 256; ++it) {  // 4
        int idx = it * 256 + t;
        int nl = idx >> 5, jj = idx & (OUTF - 1);
        int n = nodeBase + nl;
        float v = 0.f;
        if (n < NN) {
            float msum = 0.f;
            const float* S0 = &s0L[nl * HID];
            const float* S1 = &s1L[nl * HID];
#pragma unroll
            for (int f = 0; f < HID; ++f)
                msum += S0[f] * w20[f * OUTF + jj] + S1[f] * w2d[f * OUTF + jj];
            v = msum * dinv[n] + bb[jj];
            const float* hr = &hloc[nl * HID];
#pragma unroll
            for (int f = 0; f < HID; ++f)
                v = fmaf(hr[f], wr[f * OUTF + jj], v);
        }
        float m = v;
#pragma unroll
        for (int mask = 16; mask >= 1; mask >>= 1) m = fmaxf(m, __shfl_xor(m, mask));
        float ex = expf(v - m);
        float sm = ex;
#pragma unroll
        for (int mask = 16; mask >= 1; mask >>= 1) sm += __shfl_xor(sm, mask);
        if (n < NN) out[(size_t)n * OUTF + jj] = v - m - logf(sm);
    }
}

extern "C" void kernel_launch(void* const* d_in, const int* in_sizes, int n_in,
                              void* d_out, int out_size, void* d_ws, size_t ws_size,
                              hipStream_t stream) {
    const float* x     = (const float*)d_in[0];
    const int*   ei    = (const int*)d_in[1];
    const float* ea    = (const float*)d_in[3];
    const float* W1    = (const float*)d_in[4];
    const float* root1 = (const float*)d_in[5];
    const float* bias1 = (const float*)d_in[6];
    const float* W2    = (const float*)d_in[7];
    const float* root2 = (const float*)d_in[8];
    const float* bias2 = (const float*)d_in[9];
    float* out = (float*)d_out;
    float* ws  = (float*)d_ws;

    const size_t N = NN;
    int*            gcur = (int*)(ws);                        // 1563
    int*            novf = (int*)(ws + 2000);                 // 1
    int4*           ovf  = (int4*)(ws + 2048);                // OVF_MAX int4
    float*          dinv = ws + 20000;                        // 100000
    int*            segg = (int*)(ws + 120000);               // NBKT*65 = 101595
    float*          r1   = ws + 222000;                       // 16N
    unsigned*       ab1p = (unsigned*)(ws + 222000 + 16 * N); // 16N u32
    unsigned short* h16  = (unsigned short*)(ws + 222000 + 32 * N); // 16N u16
    int2*           bkt  = (int2*)(ws + 222000 + 40 * N);     // NBKT*CAP_REG int2

    int nbN = (NN + 255) / 256;
    zeroG_kernel<<<(NBKT + 256) / 256, 256, 0, stream>>>(gcur, novf);
    partF_kernel<<<PBLK2, 1024, 0, stream>>>(ei, ea, gcur, novf, ovf, bkt);
    proj1_kernel<<<nbN, 256, 0, stream>>>(x, W1, root1, bias1, ab1p, r1);
    gather1_kernel<<<NBKT, 256, 0, stream>>>(gcur, novf, ovf, bkt, ab1p, r1, h16, dinv, segg);
    gather2_kernel<<<NBKT * 2, 256, 0, stream>>>(gcur, novf, ovf, bkt, h16, W2, root2, bias2, dinv, segg, out);
}

// Round 14
// 117.271 us; speedup vs baseline: 1.0630x; 1.0234x over previous
//
#include <hip/hip_runtime.h>
#include <math.h>

#define NN 100000
#define NE 1600000
#define F_IN 64
#define HID 16
#define OUTF 32
#define BKT_SHIFT 6
#define BKT_NODES 64
#define NBKT 1563               // ceil(NN/64)
#define SRCM 0x1FFFF
#define CAP_REG 2048            // fixed region per bucket (mean 1024, sd 32)
#define CAP_LDS 1184            // fast-path LDS sort capacity (5 sigma; legacy covers rest)
#define PBLK2 500
#define EPB2 3200               // 500*3200 = 1.6M exact
#define OVF_MAX 4096

__device__ __forceinline__ unsigned bf16r(float f) {
    unsigned u = __float_as_uint(f);
    return (u + 0x7FFFu + ((u >> 16) & 1u)) >> 16;
}
__device__ __forceinline__ float bfa(unsigned p) { return __uint_as_float(p << 16); }
__device__ __forceinline__ float bfd(unsigned p) { return __uint_as_float(p & 0xFFFF0000u); }
__device__ __forceinline__ float bfh(unsigned short v) { return __uint_as_float(((unsigned)v) << 16); }

__device__ __forceinline__ void acc8(uint4 hv, float u, float* s0, float* s1) {
    unsigned w[4] = {hv.x, hv.y, hv.z, hv.w};
#pragma unroll
    for (int q = 0; q < 4; ++q) {
        float lo = __uint_as_float(w[q] << 16);
        float hi = __uint_as_float(w[q] & 0xFFFF0000u);
        s0[2 * q]     += lo; s1[2 * q]     = fmaf(u, lo, s1[2 * q]);
        s0[2 * q + 1] += hi; s1[2 * q + 1] = fmaf(u, hi, s1[2 * q + 1]);
    }
}
__device__ __forceinline__ void acc4(uint4 ap, float u, float* a) {
    unsigned w[4] = {ap.x, ap.y, ap.z, ap.w};
#pragma unroll
    for (int q = 0; q < 4; ++q)
        a[q] += fmaf(u, bfd(w[q]), bfa(w[q]));
}

__global__ __launch_bounds__(256) void zeroG_kernel(int* __restrict__ gcur,
                                                    int* __restrict__ novf) {
    int t = blockIdx.x * 256 + threadIdx.x;
    if (t < NBKT) gcur[t] = 0;
    if (t == NBKT) novf[0] = 0;
}

// ---- fused partition (unchanged) ----
__global__ __launch_bounds__(1024) void partF_kernel(const int* __restrict__ ei,
                                                     const float* __restrict__ ea,
                                                     int* __restrict__ gcur,
                                                     int* __restrict__ novf,
                                                     int4* __restrict__ ovf,
                                                     int2* __restrict__ bkt) {
    __shared__ int hcnt[NBKT];
    __shared__ int hbase[NBKT];
    __shared__ int lbase[NBKT];
    __shared__ int s[1024];
    __shared__ int2 sbuf[EPB2];
    __shared__ unsigned short bid[EPB2];
    int t = threadIdx.x, blk = blockIdx.x;
    for (int i = t; i < NBKT; i += 1024) hcnt[i] = 0;
    __syncthreads();
    int beg = blk * EPB2;
    int4 d4 = make_int4(0, 0, 0, 0);
    bool act = (4 * t) < EPB2;
    if (act) {
        d4 = *(const int4*)(ei + NE + beg + 4 * t);
        atomicAdd(&hcnt[d4.x >> BKT_SHIFT], 1);
        atomicAdd(&hcnt[d4.y >> BKT_SHIFT], 1);
        atomicAdd(&hcnt[d4.z >> BKT_SHIFT], 1);
        atomicAdd(&hcnt[d4.w >> BKT_SHIFT], 1);
    }
    __syncthreads();
    int i0 = 2 * t, i1 = 2 * t + 1;
    int v0 = (i0 < NBKT) ? hcnt[i0] : 0;
    int v1 = (i1 < NBKT) ? hcnt[i1] : 0;
    s[t] = v0 + v1;
    __syncthreads();
    for (int off = 1; off < 1024; off <<= 1) {
        int xv = (t >= off) ? s[t - off] : 0;
        __syncthreads();
        s[t] += xv;
        __syncthreads();
    }
    int run = (t == 0) ? 0 : s[t - 1];
    if (i0 < NBKT) lbase[i0] = run;
    if (i1 < NBKT) lbase[i1] = run + v0;
    __syncthreads();
    for (int i = t; i < NBKT; i += 1024) {
        int c = hcnt[i];
        hbase[i] = c ? atomicAdd(&gcur[i], c) : 0;
        hcnt[i] = 0;
    }
    __syncthreads();
    if (act) {
        int4 s4 = *(const int4*)(ei + beg + 4 * t);
        float4 u4 = *(const float4*)(ea + beg + 4 * t);
        int dst[4] = {d4.x, d4.y, d4.z, d4.w};
        int src[4] = {s4.x, s4.y, s4.z, s4.w};
        float uu[4] = {u4.x, u4.y, u4.z, u4.w};
#pragma unroll
        for (int k = 0; k < 4; ++k) {
            int b = dst[k] >> BKT_SHIFT;
            int r = atomicAdd(&hcnt[b], 1);
            int lp = lbase[b] + r;
            sbuf[lp] = make_int2(src[k] | ((dst[k] & (BKT_NODES - 1)) << 17),
                                 __float_as_int(uu[k]));
            bid[lp] = (unsigned short)b;
        }
    }
    __syncthreads();
    for (int i = t; i < EPB2; i += 1024) {
        int2 pk = sbuf[i];
        int b = bid[i];
        int p = hbase[b] + (i - lbase[b]);
        if (p < CAP_REG) {
            bkt[(size_t)b * CAP_REG + p] = pk;
        } else {
            int o = atomicAdd(novf, 1);
            if (o < OVF_MAX)
                ovf[o] = make_int4(b * BKT_NODES + (((unsigned)pk.x) >> 17), pk.x & SRCM, pk.y, 0);
        }
    }
}

// ---- layer-1 projection (unchanged) ----
__global__ __launch_bounds__(256) void proj1_kernel(const float* __restrict__ x,
                                                    const float* __restrict__ W1,
                                                    const float* __restrict__ root1,
                                                    const float* __restrict__ bias1,
                                                    unsigned* __restrict__ ab1p,
                                                    float* __restrict__ r1) {
    __shared__ float w[2 * F_IN * HID];
    __shared__ float wr[F_IN * HID];
    __shared__ float bb[HID];
    for (int i = threadIdx.x; i < 2 * F_IN * HID; i += 256) w[i] = W1[i];
    for (int i = threadIdx.x; i < F_IN * HID; i += 256) wr[i] = root1[i];
    if (threadIdx.x < HID) bb[threadIdx.x] = bias1[threadIdx.x];
    __syncthreads();
    int n = blockIdx.x * 256 + threadIdx.x;
    if (n >= NN) return;
    float accA[HID], accB[HID], accR[HID];
#pragma unroll
    for (int o = 0; o < HID; ++o) { accA[o] = 0.f; accB[o] = 0.f; accR[o] = bb[o]; }
    const float4* xr4 = (const float4*)(x + (size_t)n * F_IN);
    for (int f4 = 0; f4 < F_IN / 4; ++f4) {
        float4 xv4 = xr4[f4];
        float xs[4] = {xv4.x, xv4.y, xv4.z, xv4.w};
#pragma unroll
        for (int q = 0; q < 4; ++q) {
            int f = f4 * 4 + q;
            float xv = xs[q];
            const float* w0 = &w[f * HID];
            const float* w1 = &w[F_IN * HID + f * HID];
            const float* w2 = &wr[f * HID];
#pragma unroll
            for (int o = 0; o < HID; ++o) {
                accA[o] = fmaf(xv, w0[o], accA[o]);
                accB[o] = fmaf(xv, w1[o], accB[o]);
                accR[o] = fmaf(xv, w2[o], accR[o]);
            }
        }
    }
    unsigned* ar = ab1p + (size_t)n * HID;
    float* rr = r1 + (size_t)n * HID;
#pragma unroll
    for (int o = 0; o < HID; ++o) {
        ar[o] = bf16r(accA[o]) | (bf16r(accB[o] - accA[o]) << 16);
        rr[o] = accR[o];
    }
}

// ---- layer-1: count+scatter from global; 4 lanes/node accumulate; persist sorted+segg ----
__global__ __launch_bounds__(256) void gather1_kernel(const int* __restrict__ gcur,
                                                      const int* __restrict__ novf,
                                                      const int4* __restrict__ ovf,
                                                      int2* __restrict__ bkt,
                                                      const unsigned* __restrict__ ab1p,
                                                      const float* __restrict__ r1,
                                                      unsigned short* __restrict__ h16,
                                                      float* __restrict__ dinv,
                                                      int* __restrict__ segg) {
    __shared__ int2 sorted[CAP_LDS];        // 9.5 KB
    __shared__ int cnt[BKT_NODES], cur[BKT_NODES], segb[BKT_NODES + 1];
    __shared__ float degsL[BKT_NODES];
    int t = threadIdx.x;
    int b = blockIdx.x;
    int tot = gcur[b];
    int beg = b * CAP_REG;
    if (t < BKT_NODES) { cnt[t] = 0; cur[t] = 0; degsL[t] = 0.f; }
    __syncthreads();
    int nodeBase = b * BKT_NODES;

    if (tot <= CAP_LDS) {
        for (int e = t; e < tot; e += 256)
            atomicAdd(&cnt[((unsigned)bkt[beg + e].x) >> 17], 1);
        __syncthreads();
        if (t < BKT_NODES) {
            int v = cnt[t];
            int sc = v;
#pragma unroll
            for (int off = 1; off < 64; off <<= 1) {
                int o = __shfl_up(sc, off, 64);
                if (t >= off) sc += o;
            }
            segb[t] = sc - v;
            if (t == 63) segb[64] = sc;
        }
        __syncthreads();
        for (int e = t; e < tot; e += 256) {
            int2 pk = bkt[beg + e];
            int loc = ((unsigned)pk.x) >> 17;
            int pos = segb[loc] + atomicAdd(&cur[loc], 1);
            sorted[pos] = pk;
        }
        __syncthreads();
        int nv = tot >> 1;
        int4* s4 = (int4*)sorted;
        int4* o4 = (int4*)(bkt + beg);
        for (int i = t; i < nv; i += 256) o4[i] = s4[i];
        if (t == 0 && (tot & 1)) bkt[beg + tot - 1] = sorted[tot - 1];
        if (t <= BKT_NODES) segg[b * (BKT_NODES + 1) + t] = segb[t];
        int node = t >> 2;
        int jq = t & 3;
        int s0 = segb[node], e2 = segb[node + 1];
        float acc[4] = {0.f, 0.f, 0.f, 0.f};
        int e = s0;
        for (; e + 3 < e2; e += 4) {
            int2 p0 = sorted[e];
            int2 p1 = sorted[e + 1];
            int2 p2 = sorted[e + 2];
            int2 p3 = sorted[e + 3];
            uint4 a0 = *(const uint4*)(ab1p + ((size_t)(p0.x & SRCM) << 4) + (jq << 2));
            uint4 a1 = *(const uint4*)(ab1p + ((size_t)(p1.x & SRCM) << 4) + (jq << 2));
            uint4 a2 = *(const uint4*)(ab1p + ((size_t)(p2.x & SRCM) << 4) + (jq << 2));
            uint4 a3 = *(const uint4*)(ab1p + ((size_t)(p3.x & SRCM) << 4) + (jq << 2));
            acc4(a0, __int_as_float(p0.y), acc);
            acc4(a1, __int_as_float(p1.y), acc);
            acc4(a2, __int_as_float(p2.y), acc);
            acc4(a3, __int_as_float(p3.y), acc);
        }
        for (; e < e2; ++e) {
            int2 pk = sorted[e];
            uint4 ap = *(const uint4*)(ab1p + ((size_t)(pk.x & SRCM) << 4) + (jq << 2));
            acc4(ap, __int_as_float(pk.y), acc);
        }
        int n = nodeBase + node;
        if (n < NN) {
            float d0 = 1.f / (float)max(e2 - s0, 1);
            float4 rv = *(const float4*)(r1 + ((size_t)n << 4) + (jq << 2));
            float rr[4] = {rv.x, rv.y, rv.z, rv.w};
            unsigned hw[4];
#pragma unroll
            for (int k = 0; k < 4; ++k) {
                float v = acc[k] * d0 + rr[k];
                hw[k] = bf16r(v > 0.f ? v : expm1f(v));
            }
            *(uint2*)(h16 + ((size_t)n << 4) + (jq << 2)) =
                make_uint2(hw[0] | (hw[1] << 16), hw[2] | (hw[3] << 16));
            if (jq == 0) dinv[n] = d0;
        }
    } else {
        // ---- legacy atomic path (statistically never) ----
        float* accL = (float*)sorted;
        int inreg = min(tot, CAP_REG);
        int end = beg + inreg;
        for (int i = t; i < BKT_NODES * HID; i += 256) accL[i] = 0.f;
        __syncthreads();
        int j = t & (HID - 1);
        int g = t >> 4;
        for (int e = beg + g; e < end; e += 16) {
            int2 pk = bkt[e];
            unsigned p = ab1p[(size_t)(pk.x & SRCM) * HID + j];
            atomicAdd(&accL[(((unsigned)pk.x) >> 17) * HID + j],
                      fmaf(__int_as_float(pk.y), bfd(p), bfa(p)));
            if (j == 0) atomicAdd(&degsL[((unsigned)pk.x) >> 17], 1.f);
        }
        int ovn = min(novf[0], OVF_MAX);
        for (int o = 0; o < ovn; ++o) {
            int4 ent = ovf[o];
            int loc = ent.x - nodeBase;
            if (loc >= 0 && loc < BKT_NODES && g == 0) {
                unsigned p = ab1p[(size_t)ent.y * HID + j];
                atomicAdd(&accL[loc * HID + j], fmaf(__int_as_float(ent.z), bfd(p), bfa(p)));
                if (j == 0) atomicAdd(&degsL[loc], 1.f);
            }
        }
        __syncthreads();
        if (t < BKT_NODES) degsL[t] = 1.f / fmaxf(degsL[t], 1.f);
        if (t == 0) segg[b * (BKT_NODES + 1)] = -1;
        __syncthreads();
        for (int idx = t; idx < BKT_NODES * HID; idx += 256) {
            int nl = idx >> 4, jj = idx & (HID - 1);
            int n = nodeBase + nl;
            if (n < NN) {
                float v = accL[idx] * degsL[nl] + r1[(size_t)n * HID + jj];
                h16[(size_t)n * HID + jj] = (unsigned short)bf16r(v > 0.f ? v : expm1f(v));
            }
        }
        if (t < BKT_NODES && nodeBase + t < NN) dinv[nodeBase + t] = degsL[t];
    }
}

// ---- layer-2: 6.4 KB LDS, register S0/S1, in-wave epilogue ----
#define HB_NODES 32
__global__ __launch_bounds__(256) void gather2_kernel(const int* __restrict__ gcur,
                                                      const int* __restrict__ novf,
                                                      const int4* __restrict__ ovf,
                                                      const int2* __restrict__ bkt,
                                                      const unsigned short* __restrict__ h16,
                                                      const float* __restrict__ W2,
                                                      const float* __restrict__ root2,
                                                      const float* __restrict__ bias2,
                                                      const float* __restrict__ dinv,
                                                      const int* __restrict__ segg,
                                                      float* __restrict__ out) {
    __shared__ float w20[HID * OUTF], w2d[HID * OUTF], wr[HID * OUTF];  // 6 KB
    __shared__ float bb[OUTF];
    __shared__ int segb[HB_NODES + 1];
    __shared__ int sflag;
    int t = threadIdx.x;
    int b2 = blockIdx.x;
    int b = b2 >> 1;
    int h = b2 & 1;
    for (int i = t; i < HID * OUTF; i += 256) {
        float a = W2[i];
        w20[i] = a;
        w2d[i] = W2[HID * OUTF + i] - a;
        wr[i] = root2[i];
    }
    if (t < OUTF) bb[t] = bias2[t];
    int tot = gcur[b];
    int beg = b * CAP_REG;
    int nodeBase = b * BKT_NODES + h * HB_NODES;
    if (t <= HB_NODES) segb[t] = segg[b * (BKT_NODES + 1) + h * HB_NODES + t];
    if (t == 0) sflag = segg[b * (BKT_NODES + 1)];
    __syncthreads();

    int node = t >> 3;   // 0..31
    int li = t & 7;      // lane within node group (same wave)
    int sub = li >> 1;   // 0..3
    int jh = li & 1;     // feature half
    float S0[8] = {0.f, 0.f, 0.f, 0.f, 0.f, 0.f, 0.f, 0.f};
    float S1[8] = {0.f, 0.f, 0.f, 0.f, 0.f, 0.f, 0.f, 0.f};

    if (tot <= CAP_LDS && sflag != -1) {
        const int2* sp = bkt + beg;   // pre-sorted by gather1
        int s = segb[node], e2 = segb[node + 1];
        int e = s + sub;
        for (; e + 12 < e2; e += 16) {
            int2 p0 = sp[e];
            int2 p1 = sp[e + 4];
            int2 p2 = sp[e + 8];
            int2 p3 = sp[e + 12];
            uint4 h0 = *(const uint4*)(h16 + ((size_t)(p0.x & SRCM) << 4) + (jh << 3));
            uint4 h1 = *(const uint4*)(h16 + ((size_t)(p1.x & SRCM) << 4) + (jh << 3));
            uint4 h2 = *(const uint4*)(h16 + ((size_t)(p2.x & SRCM) << 4) + (jh << 3));
            uint4 h3 = *(const uint4*)(h16 + ((size_t)(p3.x & SRCM) << 4) + (jh << 3));
            acc8(h0, __int_as_float(p0.y), S0, S1);
            acc8(h1, __int_as_float(p1.y), S0, S1);
            acc8(h2, __int_as_float(p2.y), S0, S1);
            acc8(h3, __int_as_float(p3.y), S0, S1);
        }
        for (; e < e2; e += 4) {
            int2 pk = sp[e];
            uint4 hv = *(const uint4*)(h16 + ((size_t)(pk.x & SRCM) << 4) + (jh << 3));
            acc8(hv, __int_as_float(pk.y), S0, S1);
        }
        // reduce over sub (xor 2, 4) -> every lane holds full sums for its jh half
#pragma unroll
        for (int k = 0; k < 8; ++k) {
            S0[k] += __shfl_xor(S0[k], 2); S0[k] += __shfl_xor(S0[k], 4);
            S1[k] += __shfl_xor(S1[k], 2); S1[k] += __shfl_xor(S1[k], 4);
        }
    } else {
        // ---- legacy: alias w20/w2d as s0/s1 scratch, then reload weights ----
        float* s0L = w20;
        float* s1L = w2d;
        for (int i = t; i < HB_NODES * HID; i += 256) { s0L[i] = 0.f; s1L[i] = 0.f; }
        __syncthreads();
        int j = t & (HID - 1);
        int g = t >> 4;
        int inreg = min(tot, CAP_REG);
        int end = beg + inreg;
        for (int e = beg + g; e < end; e += 16) {
            int2 pk = bkt[e];
            int loc = ((unsigned)pk.x) >> 17;
            if ((loc >> 5) == h) {
                float hvv = bfh(h16[(size_t)(pk.x & SRCM) * HID + j]);
                atomicAdd(&s0L[(loc & 31) * HID + j], hvv);
                atomicAdd(&s1L[(loc & 31) * HID + j], __int_as_float(pk.y) * hvv);
            }
        }
        int ovn = min(novf[0], OVF_MAX);
        for (int o = 0; o < ovn; ++o) {
            int4 ent = ovf[o];
            int loc = ent.x - nodeBase;
            if (loc >= 0 && loc < HB_NODES && g == 0) {
                float hvv = bfh(h16[(size_t)ent.y * HID + j]);
                atomicAdd(&s0L[loc * HID + j], hvv);
                atomicAdd(&s1L[loc * HID + j], __int_as_float(ent.z) * hvv);
            }
        }
        __syncthreads();
        // pull into fast-path register layout
#pragma unroll
        for (int k = 0; k < 8; ++k) {
            S0[k] = s0L[node * HID + jh * 8 + k];
            S1[k] = s1L[node * HID + jh * 8 + k];
        }
        __syncthreads();
        // reload weights
        for (int i = t; i < HID * OUTF; i += 256) {
            float a = W2[i];
            w20[i] = a;
            w2d[i] = W2[HID * OUTF + i] - a;
        }
        __syncthreads();
    }

    // exchange halves with jh-partner; build full F0/F1[16]
    float F0[16], F1[16];
#pragma unroll
    for (int k = 0; k < 8; ++k) {
        float p0 = __shfl_xor(S0[k], 1);
        float p1 = __shfl_xor(S1[k], 1);
        F0[k] = jh ? p0 : S0[k];
        F0[8 + k] = jh ? S0[k] : p0;
        F1[k] = jh ? p1 : S1[k];
        F1[8 + k] = jh ? S1[k] : p1;
    }
    int n = nodeBase + node;
    if (n < NN) {
        float di = dinv[n];
        uint4 hA = *(const uint4*)(h16 + ((size_t)n << 4));
        uint4 hB = *(const uint4*)(h16 + ((size_t)n << 4) + 8);
        float hf[16];
        unsigned wa[4] = {hA.x, hA.y, hA.z, hA.w};
        unsigned wb[4] = {hB.x, hB.y, hB.z, hB.w};
#pragma unroll
        for (int q = 0; q < 4; ++q) {
            hf[2 * q]     = __uint_as_float(wa[q] << 16);
            hf[2 * q + 1] = __uint_as_float(wa[q] & 0xFFFF0000u);
            hf[8 + 2 * q]     = __uint_as_float(wb[q] << 16);
            hf[8 + 2 * q + 1] = __uint_as_float(wb[q] & 0xFFFF0000u);
        }
        float outv[4];
#pragma unroll
        for (int q = 0; q < 4; ++q) {
            int jj = li * 4 + q;
            float ms = 0.f;
#pragma unroll
            for (int f = 0; f < HID; ++f)
                ms += F0[f] * w20[f * OUTF + jj] + F1[f] * w2d[f * OUTF + jj];
            float v = ms * di + bb[jj];
#pragma unroll
            for (int f = 0; f < HID; ++f)
                v = fmaf(hf[f], wr[f * OUTF + jj], v);
            outv[q] = v;
        }
        // log_softmax across 8-lane group (32 outputs)
        float m = fmaxf(fmaxf(outv[0], outv[1]), fmaxf(outv[2], outv[3]));
        m = fmaxf(m, __shfl_xor(m, 1));
        m = fmaxf(m, __shfl_xor(m, 2));
        m = fmaxf(m, __shfl_xor(m, 4));
        float sl = expf(outv[0] - m) + expf(outv[1] - m) + expf(outv[2] - m) + expf(outv[3] - m);
        sl += __shfl_xor(sl, 1);
        sl += __shfl_xor(sl, 2);
        sl += __shfl_xor(sl, 4);
        float lse = m + logf(sl);
        *(float4*)(out + (size_t)n * OUTF + li * 4) =
            make_float4(outv[0] - lse, outv[1] - lse, outv[2] - lse, outv[3] - lse);
    }
}

extern "C" void kernel_launch(void* const* d_in, const int* in_sizes, int n_in,
                              void* d_out, int out_size, void* d_ws, size_t ws_size,
                              hipStream_t stream) {
    const float* x     = (const float*)d_in[0];
    const int*   ei    = (const int*)d_in[1];
    const float* ea    = (const float*)d_in[3];
    const float* W1    = (const float*)d_in[4];
    const float* root1 = (const float*)d_in[5];
    const float* bias1 = (const float*)d_in[6];
    const float* W2    = (const float*)d_in[7];
    const float* root2 = (const float*)d_in[8];
    const float* bias2 = (const float*)d_in[9];
    float* out = (float*)d_out;
    float* ws  = (float*)d_ws;

    const size_t N = NN;
    int*            gcur = (int*)(ws);                        // 1563
    int*            novf = (int*)(ws + 2000);                 // 1
    int4*           ovf  = (int4*)(ws + 2048);                // OVF_MAX int4
    float*          dinv = ws + 20000;                        // 100000
    int*            segg = (int*)(ws + 120000);               // NBKT*65 = 101595
    float*          r1   = ws + 222000;                       // 16N
    unsigned*       ab1p = (unsigned*)(ws + 222000 + 16 * N); // 16N u32
    unsigned short* h16  = (unsigned short*)(ws + 222000 + 32 * N); // 16N u16
    int2*           bkt  = (int2*)(ws + 222000 + 40 * N);     // NBKT*CAP_REG int2

    int nbN = (NN + 255) / 256;
    zeroG_kernel<<<(NBKT + 256) / 256, 256, 0, stream>>>(gcur, novf);
    partF_kernel<<<PBLK2, 1024, 0, stream>>>(ei, ea, gcur, novf, ovf, bkt);
    proj1_kernel<<<nbN, 256, 0, stream>>>(x, W1, root1, bias1, ab1p, r1);
    gather1_kernel<<<NBKT, 256, 0, stream>>>(gcur, novf, ovf, bkt, ab1p, r1, h16, dinv, segg);
    gather2_kernel<<<NBKT * 2, 256, 0, stream>>>(gcur, novf, ovf, bkt, h16, W2, root2, bias2, dinv, segg, out);
}